// Round 1
// baseline (277.738 us; speedup 1.0000x reference)
//
#include <hip/hip_runtime.h>
#include <hip/hip_cooperative_groups.h>

namespace cg = cooperative_groups;

using f32x4 = __attribute__((ext_vector_type(4))) float;
using s16x8 = __attribute__((ext_vector_type(8))) short;

static __device__ __forceinline__ unsigned short f2bf(float f){
  union { float f; unsigned int i; } c; c.f = f;
  return (unsigned short)((c.i + 0x7FFFu + ((c.i >> 16) & 1u)) >> 16);
}
static __device__ __forceinline__ s16x8 ld8(const unsigned short* p){
  return *(const s16x8*)p;
}
static __device__ __forceinline__ s16x8 cvt8(const float* p){
  const float4* q = (const float4*)p;
  float4 a = q[0], b = q[1];
  s16x8 r;
  r[0]=(short)f2bf(a.x); r[1]=(short)f2bf(a.y); r[2]=(short)f2bf(a.z); r[3]=(short)f2bf(a.w);
  r[4]=(short)f2bf(b.x); r[5]=(short)f2bf(b.y); r[6]=(short)f2bf(b.z); r[7]=(short)f2bf(b.w);
  return r;
}
static __device__ __forceinline__ f32x4 mfma16(s16x8 a, s16x8 b, f32x4 c){
  return __builtin_amdgcn_mfma_f32_16x16x32_bf16(a, b, c, 0, 0, 0);
}

struct Params {
  const float *x; const int *ranks;
  const float *Wp, *bp, *Wq, *bq, *Wk, *bk, *Wv, *bv;
  const float *Ee, *Wr1, *br1, *Wr2;
  const float *Wf1, *bf1, *Wf2, *bf2, *lng, *lnb, *Ws1, *bs1, *Ws2, *bs2;
  unsigned short *qg, *kg, *vg;
  float *out;
};

// ================= fused cooperative kernel =================
// 256 blocks x 512 thr (8 waves), 1 block/CU, 118528 B LDS, ONE grid.sync().
// Block p: proj rows [32p,32p+32) -> grid.sync -> attn tiles (2p,2p+1)
// (= rows [32p,32p+32), ao kept in LDS) -> ffn rows [32p,32p+32).
//
// LDS layout (bytes):
//  persistent: r_s[512]i32 @0 | rt_s[64]f32 @2048 | pmax[8][16] @2304 |
//              psum[8][16] @2816 | aoS[32*72]bf16 @3328
//  ffn weights: Wf1t[128*72] @7936 | Wf2t[64*136] @26368 | Ws1t[32*72] @43776 |
//               cb[384]f32 @48384
//  scratch @49920 (68608 B), phase-unioned:
//    proj: WpT 64*264 | Wt3 3*64*72 | xs 2*16*72
//    attn: Pbuf 8*16*136 bf16 | Opart 8*16*66 f32
//    ffn:  hbuf 2*16*136 bf16
__global__ __launch_bounds__(512, 2) void k_fused(Params P)
{
  __shared__ __align__(16) char sm[118528];
  int*   r_s    = (int*)  sm;
  float* rt_s   = (float*)(sm + 2048);
  float* pmax_s = (float*)(sm + 2304);
  float* psum_s = (float*)(sm + 2816);
  unsigned short* aoS  = (unsigned short*)(sm + 3328);
  unsigned short* Wf1t = (unsigned short*)(sm + 7936);
  unsigned short* Wf2t = (unsigned short*)(sm + 26368);
  unsigned short* Ws1t = (unsigned short*)(sm + 43776);
  float* cb            = (float*)(sm + 48384);
  char* scr = sm + 49920;
  unsigned short* WpT  = (unsigned short*)scr;             // proj view
  unsigned short* Wt3  = (unsigned short*)(scr + 33792);
  unsigned short* xs   = (unsigned short*)(scr + 61440);
  unsigned short* Pbuf = (unsigned short*)scr;             // attn view
  float*          Opart= (float*)(scr + 34816);
  unsigned short* hbuf = (unsigned short*)scr;             // ffn view

  int t = threadIdx.x, bid = blockIdx.x;
  int lane = t & 63, wave = t >> 6, colL = lane & 15, quad = lane >> 4;

  // ---- phase 0: stage proj weights (all 512 thr) + ranks ----
  for (int i = t; i < 256*64; i += 512){ int k = i >> 6, n = i & 63; WpT[n*264 + k] = f2bf(P.Wp[i]); }
  for (int i = t; i < 64*64; i += 512){
    int k2 = i >> 6, n = i & 63;
    Wt3[       n*72 + k2] = f2bf(P.Wq[i]);
    Wt3[4608 + n*72 + k2] = f2bf(P.Wk[i]);
    Wt3[9216 + n*72 + k2] = f2bf(P.Wv[i]);
  }
  r_s[t] = P.ranks[(bid >> 4)*512 + t];   // batch of this block's attn tiles
  __syncthreads();

  // ---- phase 1: waves 0-1 proj GEMMs; waves 2-6 stage ffn weights; wave 7 rel table ----
  if (wave < 2){
    int row0 = bid*32 + wave*16;
    const float* xr = P.x + (row0 + colL)*256;
    f32x4 acc[4] = {};
    for (int kc = 0; kc < 256; kc += 32){
      s16x8 a = cvt8(xr + kc + quad*8);
#pragma unroll
      for (int nt = 0; nt < 4; ++nt)
        acc[nt] = mfma16(a, ld8(&WpT[(nt*16+colL)*264 + kc + quad*8]), acc[nt]);
    }
    unsigned short* xw = xs + wave*(16*72);
#pragma unroll
    for (int nt = 0; nt < 4; ++nt){
      int col = nt*16 + colL;
      float bb = P.bp[col];
#pragma unroll
      for (int i = 0; i < 4; ++i)
        xw[(quad*4+i)*72 + col] = f2bf(acc[nt][i] + bb);
    }
    // own-wave LDS write->read: compiler inserts lgkmcnt wait; no barrier needed
    s16x8 a0 = ld8(&xw[colL*72 +  0 + quad*8]);
    s16x8 a1 = ld8(&xw[colL*72 + 32 + quad*8]);
#pragma unroll
    for (int w = 0; w < 3; ++w){
      const float* bias = w==0 ? P.bq : (w==1 ? P.bk : P.bv);
      const unsigned short* Wt = Wt3 + w*4608;
      f32x4 c[4] = {};
#pragma unroll
      for (int nt = 0; nt < 4; ++nt){
        c[nt] = mfma16(a0, ld8(&Wt[(nt*16+colL)*72 +  0 + quad*8]), c[nt]);
        c[nt] = mfma16(a1, ld8(&Wt[(nt*16+colL)*72 + 32 + quad*8]), c[nt]);
      }
#pragma unroll
      for (int nt = 0; nt < 4; ++nt){
        int col = nt*16 + colL;
        float bb = bias[col];
#pragma unroll
        for (int i = 0; i < 4; ++i){
          int row = row0 + quad*4 + i;
          float v = c[nt][i] + bb;
          if (w == 0)      P.qg[row*64 + col] = f2bf(v);
          else if (w == 1) P.kg[row*64 + col] = f2bf(v);
          else             P.vg[(row>>9)*32768 + col*512 + (row & 511)] = f2bf(v);
        }
      }
    }
  } else if (wave == 7){
    int dd = t - 448;                       // rel table, computed per block (no global round-trip)
    if (dd < 51){
      float e[32];
#pragma unroll
      for (int j = 0; j < 32; ++j) e[j] = P.Ee[dd*32 + j];
      float w = 0.f;
      for (int h = 0; h < 16; ++h){
        float s = P.br1[h];
#pragma unroll
        for (int j = 0; j < 32; ++j) s += e[j] * P.Wr1[j*16 + h];
        w += fmaxf(s, 0.f) * P.Wr2[h];
      }
      rt_s[dd] = 1.f / (1.f + __expf(-w));
    } else {
      rt_s[dd] = 0.f;
    }
  } else {
    int u = t - 128;                        // 320 threads stage ffn weights (overlaps proj)
    for (int i = u; i < 64*128; i += 320){ int d = i>>7, j = i&127; Wf1t[j*72 + d] = f2bf(P.Wf1[i]); }
    for (int i = u; i < 128*64; i += 320){ int kx = i>>6, n = i&63; Wf2t[n*136 + kx] = f2bf(P.Wf2[i]); }
    for (int i = u; i < 64*32;  i += 320){ int d = i>>5, c = i&31; Ws1t[c*72 + d] = f2bf(P.Ws1[i]); }
    if (u < 128) cb[u] = P.bf1[u];
    if (u < 64){ cb[128+u] = P.bf2[u]; cb[192+u] = P.lng[u]; cb[256+u] = P.lnb[u]; }
    if (u < 32){ cb[320+u] = P.bs1[u]; cb[352+u] = P.Ws2[u]; }
  }

  __threadfence();            // release q/k/v to device scope
  cg::this_grid().sync();     // the ONLY grid-wide barrier
  __threadfence();            // acquire (invalidate stale lines before cross-block reads)

  // ---- phase 2: attention; group g (waves 4g..4g+3) owns tile l=2*bid+g ----
  int group = wave >> 2, kw = wave & 3;
  {
    int l = bid*2 + group;
    int b = l >> 5, qt = l & 31;
    int qrow0 = qt*16;
    const unsigned short* qp = P.qg + b*32768;
    const unsigned short* kp = P.kg + b*32768;
    const unsigned short* vp = P.vg + b*32768;

    s16x8 aq0 = ld8(qp + (qrow0+colL)*64 +  0 + quad*8);
    s16x8 aq1 = ld8(qp + (qrow0+colL)*64 + 32 + quad*8);

    int key0 = kw*128;
    f32x4 Sv[8];
#pragma unroll
    for (int mt = 0; mt < 8; ++mt){
      int key = key0 + mt*16 + colL;
      f32x4 c = {};
      c = mfma16(aq0, ld8(kp + key*64 +  0 + quad*8), c);
      c = mfma16(aq1, ld8(kp + key*64 + 32 + quad*8), c);
      Sv[mt] = c;
    }

    int rq[4];
#pragma unroll
    for (int i = 0; i < 4; ++i) rq[i] = r_s[qrow0 + quad*4 + i];

    float rmax[4] = {-1e30f,-1e30f,-1e30f,-1e30f};
#pragma unroll
    for (int mt = 0; mt < 8; ++mt){
      int rm = r_s[key0 + mt*16 + colL];
#pragma unroll
      for (int i = 0; i < 4; ++i){
        int dd = rq[i] - rm; dd = dd < 0 ? -dd : dd; dd = dd > 50 ? 50 : dd;
        float s = Sv[mt][i] * 0.125f * rt_s[dd];
        Sv[mt][i] = s;
        rmax[i] = fmaxf(rmax[i], s);
      }
    }
#pragma unroll
    for (int i = 0; i < 4; ++i){
      rmax[i] = fmaxf(rmax[i], __shfl_xor(rmax[i], 1));
      rmax[i] = fmaxf(rmax[i], __shfl_xor(rmax[i], 2));
      rmax[i] = fmaxf(rmax[i], __shfl_xor(rmax[i], 4));
      rmax[i] = fmaxf(rmax[i], __shfl_xor(rmax[i], 8));
    }
    if (colL == 0){
#pragma unroll
      for (int i = 0; i < 4; ++i) pmax_s[wave*16 + quad*4 + i] = rmax[i];
    }
    __syncthreads();
    float gmax[4];
#pragma unroll
    for (int i = 0; i < 4; ++i){
      int r = (group*4)*16 + quad*4 + i;
      gmax[i] = fmaxf(fmaxf(pmax_s[r], pmax_s[r+16]), fmaxf(pmax_s[r+32], pmax_s[r+48]));
    }
    float rsum[4] = {0.f,0.f,0.f,0.f};
#pragma unroll
    for (int mt = 0; mt < 8; ++mt){
#pragma unroll
      for (int i = 0; i < 4; ++i){
        float p = __expf(Sv[mt][i] - gmax[i]);
        Sv[mt][i] = p;
        rsum[i] += p;
      }
    }
#pragma unroll
    for (int i = 0; i < 4; ++i){
      rsum[i] += __shfl_xor(rsum[i], 1);
      rsum[i] += __shfl_xor(rsum[i], 2);
      rsum[i] += __shfl_xor(rsum[i], 4);
      rsum[i] += __shfl_xor(rsum[i], 8);
    }
    if (colL == 0){
#pragma unroll
      for (int i = 0; i < 4; ++i) psum_s[wave*16 + quad*4 + i] = rsum[i];
    }
    __syncthreads();
    float inv[4];
#pragma unroll
    for (int i = 0; i < 4; ++i){
      int r = (group*4)*16 + quad*4 + i;
      inv[i] = 1.f / (psum_s[r] + psum_s[r+16] + psum_s[r+32] + psum_s[r+48]);
    }
    unsigned short* Pw = Pbuf + wave*(16*136);
#pragma unroll
    for (int mt = 0; mt < 8; ++mt){
#pragma unroll
      for (int i = 0; i < 4; ++i)
        Pw[(quad*4+i)*136 + mt*16 + colL] = f2bf(Sv[mt][i] * inv[i]);
    }
    // PV on own-wave P (no barrier needed)
    f32x4 O[4] = {};
#pragma unroll
    for (int mc = 0; mc < 128; mc += 32){
      s16x8 ap = ld8(&Pw[colL*136 + mc + quad*8]);
#pragma unroll
      for (int dt = 0; dt < 4; ++dt)
        O[dt] = mfma16(ap, ld8(vp + (dt*16+colL)*512 + key0 + mc + quad*8), O[dt]);
    }
    float* Ow = Opart + wave*(16*66);
#pragma unroll
    for (int dt = 0; dt < 4; ++dt)
#pragma unroll
      for (int i = 0; i < 4; ++i)
        Ow[(quad*4+i)*66 + dt*16 + colL] = O[dt][i];
    __syncthreads();
    // combine 4-way key split -> ao stays in LDS (rows align with ffn phase)
    int tg = t & 255;
    const float* Og = Opart + (group*4)*(16*66);
    for (int e = tg; e < 1024; e += 256){
      int row = e >> 6, col = e & 63;
      float s = Og[row*66+col] + Og[1056 + row*66+col]
              + Og[2112 + row*66+col] + Og[3168 + row*66+col];
      aoS[(group*16 + row)*72 + col] = f2bf(s);
    }
  }
  __syncthreads();   // aoS complete; scratch (Pbuf/Opart) now dead -> reuse as hbuf

  // ---- phase 3: FFN + LayerNorm + head on own rows (waves 0-1) ----
  if (wave < 2){
    unsigned short* hw = hbuf + wave*(16*136);
    int row0 = bid*32 + wave*16;

    f32x4 a1[8] = {};
#pragma unroll
    for (int kc = 0; kc < 64; kc += 32){
      s16x8 a = ld8(&aoS[(wave*16 + colL)*72 + kc + quad*8]);
#pragma unroll
      for (int nt = 0; nt < 8; ++nt)
        a1[nt] = mfma16(a, ld8(&Wf1t[(nt*16+colL)*72 + kc + quad*8]), a1[nt]);
    }
#pragma unroll
    for (int nt = 0; nt < 8; ++nt){
      int col = nt*16 + colL;
      float bb = cb[col];
#pragma unroll
      for (int i = 0; i < 4; ++i)
        hw[(quad*4+i)*136 + col] = f2bf(fmaxf(a1[nt][i] + bb, 0.f));
    }
    f32x4 a2[4] = {};
#pragma unroll
    for (int kc = 0; kc < 128; kc += 32){
      s16x8 a = ld8(&hw[colL*136 + kc + quad*8]);
#pragma unroll
      for (int nt = 0; nt < 4; ++nt)
        a2[nt] = mfma16(a, ld8(&Wf2t[(nt*16+colL)*136 + kc + quad*8]), a2[nt]);
    }
    float vals[4][4];
#pragma unroll
    for (int nt = 0; nt < 4; ++nt){
      float bb = cb[128 + nt*16 + colL];
#pragma unroll
      for (int i = 0; i < 4; ++i) vals[i][nt] = a2[nt][i] + bb;
    }
    float hnv[4][4];
#pragma unroll
    for (int i = 0; i < 4; ++i){
      float s = vals[i][0]+vals[i][1]+vals[i][2]+vals[i][3];
      s += __shfl_xor(s,1); s += __shfl_xor(s,2); s += __shfl_xor(s,4); s += __shfl_xor(s,8);
      float mu = s * (1.f/64.f);
      float d0=vals[i][0]-mu, d1=vals[i][1]-mu, d2=vals[i][2]-mu, d3=vals[i][3]-mu;
      float s2 = d0*d0 + d1*d1 + d2*d2 + d3*d3;
      s2 += __shfl_xor(s2,1); s2 += __shfl_xor(s2,2); s2 += __shfl_xor(s2,4); s2 += __shfl_xor(s2,8);
      float invs = rsqrtf(s2*(1.f/64.f) + 1e-5f);
#pragma unroll
      for (int nt = 0; nt < 4; ++nt){
        int col = nt*16 + colL;
        hnv[i][nt] = (vals[i][nt]-mu)*invs*cb[192+col] + cb[256+col];
      }
    }
#pragma unroll
    for (int i = 0; i < 4; ++i)
#pragma unroll
      for (int nt = 0; nt < 4; ++nt)
        hw[(quad*4+i)*72 + nt*16 + colL] = f2bf(hnv[i][nt]);

    f32x4 a3[2] = {};
#pragma unroll
    for (int kc = 0; kc < 64; kc += 32){
      s16x8 a = ld8(&hw[colL*72 + kc + quad*8]);
#pragma unroll
      for (int nt = 0; nt < 2; ++nt)
        a3[nt] = mfma16(a, ld8(&Ws1t[(nt*16+colL)*72 + kc + quad*8]), a3[nt]);
    }
    float bs2f = P.bs2[0];
#pragma unroll
    for (int i = 0; i < 4; ++i){
      float p = 0.f;
#pragma unroll
      for (int nt = 0; nt < 2; ++nt){
        int col = nt*16 + colL;
        p += fmaxf(a3[nt][i] + cb[320+col], 0.f) * cb[352+col];
      }
      p += __shfl_xor(p,1); p += __shfl_xor(p,2); p += __shfl_xor(p,4); p += __shfl_xor(p,8);
      if (colL == 0){
        float z = p + bs2f;
        P.out[row0 + quad*4 + i] = 1.f / (1.f + __expf(-z));
      }
    }
  }
}

// ================= fallback path: original verified 3-kernel pipeline =================
__global__ __launch_bounds__(128) void k_proj(const float* __restrict__ x,
    const float* __restrict__ Wp, const float* __restrict__ bp,
    const float* __restrict__ Wq, const float* __restrict__ bq,
    const float* __restrict__ Wk, const float* __restrict__ bk,
    const float* __restrict__ Wv, const float* __restrict__ bv,
    const float* __restrict__ Ee, const float* __restrict__ Wr1,
    const float* __restrict__ br1, const float* __restrict__ Wr2,
    unsigned short* __restrict__ q, unsigned short* __restrict__ kk,
    unsigned short* __restrict__ vt, float* __restrict__ rel_t)
{
  __shared__ __align__(16) unsigned short WpT[64*264];
  __shared__ __align__(16) unsigned short Wt3[3][64*72];
  __shared__ __align__(16) unsigned short xs[2][16*72];

  int t = threadIdx.x;
  for (int i = t; i < 256*64; i += 128){
    int k = i >> 6, n = i & 63;
    WpT[n*264 + k] = f2bf(Wp[i]);
  }
  for (int i = t; i < 64*64; i += 128){
    int k2 = i >> 6, n = i & 63;
    Wt3[0][n*72 + k2] = f2bf(Wq[i]);
    Wt3[1][n*72 + k2] = f2bf(Wk[i]);
    Wt3[2][n*72 + k2] = f2bf(Wv[i]);
  }
  if (blockIdx.x == 0 && t < 51){
    float e[32];
    for (int j = 0; j < 32; ++j) e[j] = Ee[t*32 + j];
    float w = 0.f;
    for (int h = 0; h < 16; ++h){
      float s = br1[h];
      for (int j = 0; j < 32; ++j) s += e[j] * Wr1[j*16 + h];
      w += fmaxf(s, 0.f) * Wr2[h];
    }
    rel_t[t] = 1.f / (1.f + __expf(-w));
  }
  __syncthreads();

  int lane = t & 63, wave = t >> 6, colL = lane & 15, quad = lane >> 4;
  int row0 = blockIdx.x*32 + wave*16;

  const float* xr = x + (row0 + colL)*256;
  f32x4 acc[4] = {};
  for (int kc = 0; kc < 256; kc += 32){
    s16x8 a = cvt8(xr + kc + quad*8);
#pragma unroll
    for (int nt = 0; nt < 4; ++nt)
      acc[nt] = mfma16(a, ld8(&WpT[(nt*16+colL)*264 + kc + quad*8]), acc[nt]);
  }
  unsigned short* xw = xs[wave];
#pragma unroll
  for (int nt = 0; nt < 4; ++nt){
    int col = nt*16 + colL;
    float bb = bp[col];
#pragma unroll
    for (int i = 0; i < 4; ++i)
      xw[(quad*4+i)*72 + col] = f2bf(acc[nt][i] + bb);
  }
  s16x8 a0 = ld8(&xw[colL*72 +  0 + quad*8]);
  s16x8 a1 = ld8(&xw[colL*72 + 32 + quad*8]);

#pragma unroll
  for (int w = 0; w < 3; ++w){
    const float* bias = w==0 ? bq : (w==1 ? bk : bv);
    f32x4 c[4] = {};
#pragma unroll
    for (int nt = 0; nt < 4; ++nt){
      c[nt] = mfma16(a0, ld8(&Wt3[w][(nt*16+colL)*72 +  0 + quad*8]), c[nt]);
      c[nt] = mfma16(a1, ld8(&Wt3[w][(nt*16+colL)*72 + 32 + quad*8]), c[nt]);
    }
#pragma unroll
    for (int nt = 0; nt < 4; ++nt){
      int col = nt*16 + colL;
      float bb = bias[col];
#pragma unroll
      for (int i = 0; i < 4; ++i){
        int row = row0 + quad*4 + i;
        float v = c[nt][i] + bb;
        if (w == 0)      q [row*64 + col] = f2bf(v);
        else if (w == 1) kk[row*64 + col] = f2bf(v);
        else             vt[(row>>9)*32768 + col*512 + (row & 511)] = f2bf(v);
      }
    }
  }
}

__global__ __launch_bounds__(256) void k_attn(const unsigned short* __restrict__ q,
    const unsigned short* __restrict__ kmat, const unsigned short* __restrict__ vt,
    const int* __restrict__ ranks, const float* __restrict__ rel_t,
    unsigned short* __restrict__ ao)
{
  int b = blockIdx.y, qt = blockIdx.x;
  int t = threadIdx.x, lane = t & 63, wave = t >> 6;
  int colL = lane & 15, quad = lane >> 4;

  __shared__ int r_s[512];
  __shared__ float rt_s[64];
  __shared__ __align__(16) unsigned short Pl[4][16*136];
  __shared__ float Opart[4][16*66];
  __shared__ float pmax_s[4][16], psum_s[4][16];

  for (int i = t; i < 512; i += 256) r_s[i] = ranks[b*512 + i];
  if (t < 64) rt_s[t] = (t < 51) ? rel_t[t] : 0.f;
  __syncthreads();

  int qrow0 = qt*16;
  const unsigned short* qp = q    + b*32768;
  const unsigned short* kp = kmat + b*32768;
  const unsigned short* vp = vt   + b*32768;

  s16x8 aq0 = ld8(qp + (qrow0+colL)*64 +  0 + quad*8);
  s16x8 aq1 = ld8(qp + (qrow0+colL)*64 + 32 + quad*8);

  int key0 = wave*128;
  f32x4 S[8];
#pragma unroll
  for (int mt = 0; mt < 8; ++mt){
    int key = key0 + mt*16 + colL;
    f32x4 c = {};
    c = mfma16(aq0, ld8(kp + key*64 +  0 + quad*8), c);
    c = mfma16(aq1, ld8(kp + key*64 + 32 + quad*8), c);
    S[mt] = c;
  }

  int rq[4];
#pragma unroll
  for (int i = 0; i < 4; ++i) rq[i] = r_s[qrow0 + quad*4 + i];

  float rmax[4] = {-1e30f,-1e30f,-1e30f,-1e30f};
#pragma unroll
  for (int mt = 0; mt < 8; ++mt){
    int rm = r_s[key0 + mt*16 + colL];
#pragma unroll
    for (int i = 0; i < 4; ++i){
      int dd = rq[i] - rm; dd = dd < 0 ? -dd : dd; dd = dd > 50 ? 50 : dd;
      float s = S[mt][i] * 0.125f * rt_s[dd];
      S[mt][i] = s;
      rmax[i] = fmaxf(rmax[i], s);
    }
  }
#pragma unroll
  for (int i = 0; i < 4; ++i){
    rmax[i] = fmaxf(rmax[i], __shfl_xor(rmax[i], 1));
    rmax[i] = fmaxf(rmax[i], __shfl_xor(rmax[i], 2));
    rmax[i] = fmaxf(rmax[i], __shfl_xor(rmax[i], 4));
    rmax[i] = fmaxf(rmax[i], __shfl_xor(rmax[i], 8));
  }
  if (colL == 0){
#pragma unroll
    for (int i = 0; i < 4; ++i) pmax_s[wave][quad*4 + i] = rmax[i];
  }
  __syncthreads();
  float gmax[4];
#pragma unroll
  for (int i = 0; i < 4; ++i){
    int r = quad*4 + i;
    gmax[i] = fmaxf(fmaxf(pmax_s[0][r], pmax_s[1][r]), fmaxf(pmax_s[2][r], pmax_s[3][r]));
  }
  float rsum[4] = {0.f,0.f,0.f,0.f};
#pragma unroll
  for (int mt = 0; mt < 8; ++mt){
#pragma unroll
    for (int i = 0; i < 4; ++i){
      float p = __expf(S[mt][i] - gmax[i]);
      S[mt][i] = p;
      rsum[i] += p;
    }
  }
#pragma unroll
  for (int i = 0; i < 4; ++i){
    rsum[i] += __shfl_xor(rsum[i], 1);
    rsum[i] += __shfl_xor(rsum[i], 2);
    rsum[i] += __shfl_xor(rsum[i], 4);
    rsum[i] += __shfl_xor(rsum[i], 8);
  }
  if (colL == 0){
#pragma unroll
    for (int i = 0; i < 4; ++i) psum_s[wave][quad*4 + i] = rsum[i];
  }
  __syncthreads();
  float inv[4];
#pragma unroll
  for (int i = 0; i < 4; ++i){
    int r = quad*4 + i;
    inv[i] = 1.f / (psum_s[0][r] + psum_s[1][r] + psum_s[2][r] + psum_s[3][r]);
  }
  unsigned short* Pw = Pl[wave];
#pragma unroll
  for (int mt = 0; mt < 8; ++mt){
#pragma unroll
    for (int i = 0; i < 4; ++i)
      Pw[(quad*4+i)*136 + mt*16 + colL] = f2bf(S[mt][i] * inv[i]);
  }
  f32x4 O[4] = {};
#pragma unroll
  for (int mc = 0; mc < 128; mc += 32){
    s16x8 ap = ld8(&Pw[colL*136 + mc + quad*8]);
#pragma unroll
    for (int dt = 0; dt < 4; ++dt)
      O[dt] = mfma16(ap, ld8(vp + (dt*16+colL)*512 + key0 + mc + quad*8), O[dt]);
  }
  float* Ow = Opart[wave];
#pragma unroll
  for (int dt = 0; dt < 4; ++dt)
#pragma unroll
    for (int i = 0; i < 4; ++i)
      Ow[(quad*4+i)*66 + dt*16 + colL] = O[dt][i];
  __syncthreads();
  for (int e = t; e < 1024; e += 256){
    int row = e >> 6, col = e & 63;
    float s = Opart[0][row*66+col] + Opart[1][row*66+col]
            + Opart[2][row*66+col] + Opart[3][row*66+col];
    ao[(b*512 + qrow0 + row)*64 + col] = f2bf(s);
  }
}

__global__ __launch_bounds__(128) void k_ffn(const unsigned short* __restrict__ ao,
    const float* __restrict__ Wf1, const float* __restrict__ bf1,
    const float* __restrict__ Wf2, const float* __restrict__ bf2,
    const float* __restrict__ lng, const float* __restrict__ lnb,
    const float* __restrict__ Ws1, const float* __restrict__ bs1,
    const float* __restrict__ Ws2, const float* __restrict__ bs2,
    float* __restrict__ out)
{
  __shared__ __align__(16) unsigned short Wf1t[128*72];
  __shared__ __align__(16) unsigned short Wf2t[64*136];
  __shared__ __align__(16) unsigned short Ws1t[32*72];
  __shared__ __align__(16) unsigned short hbuf[2][16*136];
  __shared__ float cb[384];

  int t = threadIdx.x;
  for (int i = t; i < 64*128; i += 128){ int d = i>>7, j = i&127; Wf1t[j*72 + d] = f2bf(Wf1[i]); }
  for (int i = t; i < 128*64; i += 128){ int kx = i>>6, n = i&63; Wf2t[n*136 + kx] = f2bf(Wf2[i]); }
  for (int i = t; i < 64*32;  i += 128){ int d = i>>5, c = i&31; Ws1t[c*72 + d] = f2bf(Ws1[i]); }
  if (t < 128) cb[t] = bf1[t];
  if (t < 64){ cb[128+t] = bf2[t]; cb[192+t] = lng[t]; cb[256+t] = lnb[t]; }
  if (t < 32){ cb[320+t] = bs1[t]; cb[352+t] = Ws2[t]; }
  __syncthreads();

  int lane = t & 63, wave = t >> 6, colL = lane & 15, quad = lane >> 4;
  int row0 = blockIdx.x*32 + wave*16;
  unsigned short* hw = hbuf[wave];

  f32x4 a1[8] = {};
#pragma unroll
  for (int kc = 0; kc < 64; kc += 32){
    s16x8 a = ld8(ao + (row0+colL)*64 + kc + quad*8);
#pragma unroll
    for (int nt = 0; nt < 8; ++nt)
      a1[nt] = mfma16(a, ld8(&Wf1t[(nt*16+colL)*72 + kc + quad*8]), a1[nt]);
  }
#pragma unroll
  for (int nt = 0; nt < 8; ++nt){
    int col = nt*16 + colL;
    float bb = cb[col];
#pragma unroll
    for (int i = 0; i < 4; ++i)
      hw[(quad*4+i)*136 + col] = f2bf(fmaxf(a1[nt][i] + bb, 0.f));
  }
  f32x4 a2[4] = {};
#pragma unroll
  for (int kc = 0; kc < 128; kc += 32){
    s16x8 a = ld8(&hw[colL*136 + kc + quad*8]);
#pragma unroll
    for (int nt = 0; nt < 4; ++nt)
      a2[nt] = mfma16(a, ld8(&Wf2t[(nt*16+colL)*136 + kc + quad*8]), a2[nt]);
  }
  float vals[4][4];
#pragma unroll
  for (int nt = 0; nt < 4; ++nt){
    float bb = cb[128 + nt*16 + colL];
#pragma unroll
    for (int i = 0; i < 4; ++i) vals[i][nt] = a2[nt][i] + bb;
  }
  float hnv[4][4];
#pragma unroll
  for (int i = 0; i < 4; ++i){
    float s = vals[i][0]+vals[i][1]+vals[i][2]+vals[i][3];
    s += __shfl_xor(s,1); s += __shfl_xor(s,2); s += __shfl_xor(s,4); s += __shfl_xor(s,8);
    float mu = s * (1.f/64.f);
    float d0=vals[i][0]-mu, d1=vals[i][1]-mu, d2=vals[i][2]-mu, d3=vals[i][3]-mu;
    float s2 = d0*d0 + d1*d1 + d2*d2 + d3*d3;
    s2 += __shfl_xor(s2,1); s2 += __shfl_xor(s2,2); s2 += __shfl_xor(s2,4); s2 += __shfl_xor(s2,8);
    float invs = rsqrtf(s2*(1.f/64.f) + 1e-5f);
#pragma unroll
    for (int nt = 0; nt < 4; ++nt){
      int col = nt*16 + colL;
      hnv[i][nt] = (vals[i][nt]-mu)*invs*cb[192+col] + cb[256+col];
    }
  }
#pragma unroll
  for (int i = 0; i < 4; ++i)
#pragma unroll
    for (int nt = 0; nt < 4; ++nt)
      hw[(quad*4+i)*72 + nt*16 + colL] = f2bf(hnv[i][nt]);

  f32x4 a3[2] = {};
#pragma unroll
  for (int kc = 0; kc < 64; kc += 32){
    s16x8 a = ld8(&hw[colL*72 + kc + quad*8]);
#pragma unroll
    for (int nt = 0; nt < 2; ++nt)
      a3[nt] = mfma16(a, ld8(&Ws1t[(nt*16+colL)*72 + kc + quad*8]), a3[nt]);
  }
  float bs2f = bs2[0];
#pragma unroll
  for (int i = 0; i < 4; ++i){
    float p = 0.f;
#pragma unroll
    for (int nt = 0; nt < 2; ++nt){
      int col = nt*16 + colL;
      p += fmaxf(a3[nt][i] + cb[320+col], 0.f) * cb[352+col];
    }
    p += __shfl_xor(p,1); p += __shfl_xor(p,2); p += __shfl_xor(p,4); p += __shfl_xor(p,8);
    if (colL == 0){
      float z = p + bs2f;
      out[row0 + quad*4 + i] = 1.f / (1.f + __expf(-z));
    }
  }
}

extern "C" void kernel_launch(void* const* d_in, const int* in_sizes, int n_in,
                              void* d_out, int out_size, void* d_ws, size_t ws_size,
                              hipStream_t stream)
{
  const float* x    = (const float*)d_in[0];
  const int*   rank = (const int*)d_in[1];
  const float* Wp   = (const float*)d_in[2];
  const float* bp   = (const float*)d_in[3];
  const float* Wq   = (const float*)d_in[4];
  const float* bq   = (const float*)d_in[5];
  const float* Wk   = (const float*)d_in[6];
  const float* bk   = (const float*)d_in[7];
  const float* Wv   = (const float*)d_in[8];
  const float* bv   = (const float*)d_in[9];
  const float* Ee   = (const float*)d_in[10];
  const float* Wr1  = (const float*)d_in[11];
  const float* br1  = (const float*)d_in[12];
  const float* Wr2  = (const float*)d_in[13];
  const float* Wf1  = (const float*)d_in[14];
  const float* bf1  = (const float*)d_in[15];
  const float* Wf2  = (const float*)d_in[16];
  const float* bf2  = (const float*)d_in[17];
  const float* lng  = (const float*)d_in[18];
  const float* lnb  = (const float*)d_in[19];
  const float* Ws1  = (const float*)d_in[20];
  const float* bs1  = (const float*)d_in[21];
  const float* Ws2  = (const float*)d_in[22];
  const float* bs2  = (const float*)d_in[23];
  float* out = (float*)d_out;

  char* ws = (char*)d_ws;
  float*          rel_t = (float*)(ws + 0);
  unsigned short* q     = (unsigned short*)(ws + 256);
  unsigned short* kk    = (unsigned short*)(ws + 256 + 1*1048576);
  unsigned short* vt    = (unsigned short*)(ws + 256 + 2*1048576);
  unsigned short* ao    = (unsigned short*)(ws + 256 + 3*1048576);

  Params p{ x, rank, Wp, bp, Wq, bq, Wk, bk, Wv, bv,
            Ee, Wr1, br1, Wr2,
            Wf1, bf1, Wf2, bf2, lng, lnb, Ws1, bs1, Ws2, bs2,
            q, kk, vt, out };
  void* args[] = { (void*)&p };
  hipError_t err = hipLaunchCooperativeKernel(k_fused, dim3(256), dim3(512),
                                              args, 0u, stream);
  if (err != hipSuccess){
    // fallback: verified 3-kernel pipeline
    k_proj<<<dim3(256), dim3(128), 0, stream>>>(x, Wp, bp, Wq, bq, Wk, bk, Wv, bv,
                                                Ee, Wr1, br1, Wr2, q, kk, vt, rel_t);
    k_attn<<<dim3(32, 16), dim3(256), 0, stream>>>(q, kk, vt, rank, rel_t, ao);
    k_ffn<<<dim3(256), dim3(128), 0, stream>>>(ao, Wf1, bf1, Wf2, bf2, lng, lnb,
                                               Ws1, bs1, Ws2, bs2, out);
  }
}

// Round 2
// 136.077 us; speedup vs baseline: 2.0410x; 2.0410x over previous
//
#include <hip/hip_runtime.h>

using f32x4 = __attribute__((ext_vector_type(4))) float;
using s16x8 = __attribute__((ext_vector_type(8))) short;

static __device__ __forceinline__ unsigned short f2bf(float f){
  union { float f; unsigned int i; } c; c.f = f;
  return (unsigned short)((c.i + 0x7FFFu + ((c.i >> 16) & 1u)) >> 16);
}
static __device__ __forceinline__ s16x8 ld8(const unsigned short* p){
  return *(const s16x8*)p;
}
static __device__ __forceinline__ s16x8 cvt8(const float* p){
  const float4* q = (const float4*)p;
  float4 a = q[0], b = q[1];
  s16x8 r;
  r[0]=(short)f2bf(a.x); r[1]=(short)f2bf(a.y); r[2]=(short)f2bf(a.z); r[3]=(short)f2bf(a.w);
  r[4]=(short)f2bf(b.x); r[5]=(short)f2bf(b.y); r[6]=(short)f2bf(b.z); r[7]=(short)f2bf(b.w);
  return r;
}
static __device__ __forceinline__ f32x4 mfma16(s16x8 a, s16x8 b, f32x4 c){
  return __builtin_amdgcn_mfma_f32_16x16x32_bf16(a, b, c, 0, 0, 0);
}

// ============ kernel A: x -> xp -> q,k,vt; block 0 wave 2 builds rel_t ============
// grid 256 x 192thr (3 waves): waves 0-1 compute 32 rows; wave 2 stages + rel.
// All staging loads are float4 (4x fewer cold misses than scalar).
__global__ __launch_bounds__(192) void k_proj(const float* __restrict__ x,
    const float* __restrict__ Wp, const float* __restrict__ bp,
    const float* __restrict__ Wq, const float* __restrict__ bq,
    const float* __restrict__ Wk, const float* __restrict__ bk,
    const float* __restrict__ Wv, const float* __restrict__ bv,
    const float* __restrict__ Ee, const float* __restrict__ Wr1,
    const float* __restrict__ br1, const float* __restrict__ Wr2,
    unsigned short* __restrict__ q, unsigned short* __restrict__ kk,
    unsigned short* __restrict__ vt, float* __restrict__ rel_t)
{
  __shared__ __align__(16) unsigned short WpT[64*264];   // Wp^T [n][k]
  __shared__ __align__(16) unsigned short Wt3[3][64*72]; // Wq/Wk/Wv^T [n][k]
  __shared__ __align__(16) unsigned short xs[2][16*72];  // per-wave xp tile

  int t = threadIdx.x;
  int row0b = blockIdx.x*32;

  // L2-warm touch of this block's x rows (misses overlap weight staging)
  const float4* xb4 = (const float4*)(x + row0b*256);    // 2048 float4 = 256 x 128B lines
  float4 tc0 = xb4[((t*2  ) & 255)*8];
  float4 tc1 = xb4[((t*2+1) & 255)*8];

  // stage Wp^T via float4 (4096 f4 over 192 thr)
  const float4* Wp4 = (const float4*)Wp;
  for (int i = t; i < 4096; i += 192){
    float4 v = Wp4[i];
    int k = i >> 4, n = (i & 15) * 4;
    WpT[(n+0)*264+k] = f2bf(v.x);
    WpT[(n+1)*264+k] = f2bf(v.y);
    WpT[(n+2)*264+k] = f2bf(v.z);
    WpT[(n+3)*264+k] = f2bf(v.w);
  }
  const float4* Wq4 = (const float4*)Wq;
  const float4* Wk4 = (const float4*)Wk;
  const float4* Wv4 = (const float4*)Wv;
  for (int i = t; i < 1024; i += 192){
    int k = i >> 4, n = (i & 15) * 4;
    float4 a = Wq4[i], b2 = Wk4[i], c2 = Wv4[i];
    Wt3[0][(n+0)*72+k]=f2bf(a.x);  Wt3[0][(n+1)*72+k]=f2bf(a.y);
    Wt3[0][(n+2)*72+k]=f2bf(a.z);  Wt3[0][(n+3)*72+k]=f2bf(a.w);
    Wt3[1][(n+0)*72+k]=f2bf(b2.x); Wt3[1][(n+1)*72+k]=f2bf(b2.y);
    Wt3[1][(n+2)*72+k]=f2bf(b2.z); Wt3[1][(n+3)*72+k]=f2bf(b2.w);
    Wt3[2][(n+0)*72+k]=f2bf(c2.x); Wt3[2][(n+1)*72+k]=f2bf(c2.y);
    Wt3[2][(n+2)*72+k]=f2bf(c2.z); Wt3[2][(n+3)*72+k]=f2bf(c2.w);
  }
  // rel table on wave 2 of block 0 (off the compute waves' critical path)
  if (blockIdx.x == 0 && t >= 128 && t < 179){
    int dd = t - 128;
    float e[32];
    const float4* e4 = (const float4*)(Ee + dd*32);
#pragma unroll
    for (int j = 0; j < 8; ++j){
      float4 v = e4[j];
      e[j*4+0]=v.x; e[j*4+1]=v.y; e[j*4+2]=v.z; e[j*4+3]=v.w;
    }
    float w = 0.f;
    for (int h = 0; h < 16; ++h){
      float s = br1[h];
#pragma unroll
      for (int j = 0; j < 32; ++j) s += e[j] * Wr1[j*16 + h];
      w += fmaxf(s, 0.f) * Wr2[h];
    }
    rel_t[dd] = 1.f / (1.f + __expf(-w));
  }
  asm volatile("" :: "v"(tc0.x), "v"(tc1.x));   // keep touches alive (issued above)
  __syncthreads();

  if (t < 128){
    int lane = t & 63, wave = t >> 6, colL = lane & 15, quad = lane >> 4;
    int row0 = row0b + wave*16;

    const float* xr = x + (row0 + colL)*256;    // L2-warm after touch
    f32x4 acc[4] = {};
    for (int kc = 0; kc < 256; kc += 32){
      s16x8 a = cvt8(xr + kc + quad*8);
#pragma unroll
      for (int nt = 0; nt < 4; ++nt)
        acc[nt] = mfma16(a, ld8(&WpT[(nt*16+colL)*264 + kc + quad*8]), acc[nt]);
    }
    unsigned short* xw = xs[wave];
#pragma unroll
    for (int nt = 0; nt < 4; ++nt){
      int col = nt*16 + colL;
      float bb = bp[col];
#pragma unroll
      for (int i = 0; i < 4; ++i)
        xw[(quad*4+i)*72 + col] = f2bf(acc[nt][i] + bb);
    }
    // own-wave LDS write->read: compiler inserts lgkmcnt wait; no barrier needed
    s16x8 a0 = ld8(&xw[colL*72 +  0 + quad*8]);
    s16x8 a1 = ld8(&xw[colL*72 + 32 + quad*8]);

#pragma unroll
    for (int w = 0; w < 3; ++w){
      const float* bias = w==0 ? bq : (w==1 ? bk : bv);
      f32x4 c[4] = {};
#pragma unroll
      for (int nt = 0; nt < 4; ++nt){
        c[nt] = mfma16(a0, ld8(&Wt3[w][(nt*16+colL)*72 +  0 + quad*8]), c[nt]);
        c[nt] = mfma16(a1, ld8(&Wt3[w][(nt*16+colL)*72 + 32 + quad*8]), c[nt]);
      }
#pragma unroll
      for (int nt = 0; nt < 4; ++nt){
        int col = nt*16 + colL;
        float bb = bias[col];
#pragma unroll
        for (int i = 0; i < 4; ++i){
          int row = row0 + quad*4 + i;
          float v = c[nt][i] + bb;
          if (w == 0)      q [row*64 + col] = f2bf(v);
          else if (w == 1) kk[row*64 + col] = f2bf(v);
          else             vt[(row>>9)*32768 + col*512 + (row & 511)] = f2bf(v);
        }
      }
    }
  }
}

// ============ kernel B: attention + FFN + LN + head, fused per 16-row q-tile ============
// grid (32 qtiles, 16 batches) x 256thr. Waves 0-3 split keys 4-way for attn;
// FFN weight staging is issued BEFORE QK^T so its cold misses drain under compute.
// ao never leaves LDS. LDS total 79104 B -> 2 blocks/CU.
__global__ __launch_bounds__(256) void k_attn_ffn(const unsigned short* __restrict__ q,
    const unsigned short* __restrict__ kmat, const unsigned short* __restrict__ vt,
    const int* __restrict__ ranks, const float* __restrict__ rel_t,
    const float* __restrict__ Wf1, const float* __restrict__ bf1,
    const float* __restrict__ Wf2, const float* __restrict__ bf2,
    const float* __restrict__ lng, const float* __restrict__ lnb,
    const float* __restrict__ Ws1, const float* __restrict__ bs1,
    const float* __restrict__ Ws2, const float* __restrict__ bs2,
    float* __restrict__ out)
{
  __shared__ __align__(16) int r_s[512];
  __shared__ float rt_s[64];
  __shared__ float pmax_s[4][16], psum_s[4][16];
  __shared__ __align__(16) unsigned short Pbuf[4*16*136]; // P; later aoS(@0)+hbuf(@2176)
  __shared__ __align__(16) float Opart[4][16*66];
  __shared__ __align__(16) unsigned short Wf1t[128*72];
  __shared__ __align__(16) unsigned short Wf2t[64*136];
  __shared__ __align__(16) unsigned short Ws1t[32*72];
  __shared__ float cb[384];

  int b = blockIdx.y, qt = blockIdx.x;
  int t = threadIdx.x, lane = t & 63, wave = t >> 6;
  int colL = lane & 15, quad = lane >> 4;

  // ---- issue all staging first (cold HBM misses overlap the QK^T below) ----
  if (t < 128) ((int4*)r_s)[t] = ((const int4*)(ranks + b*512))[t];
  if (t < 64) rt_s[t] = (t < 51) ? rel_t[t] : 0.f;
  const float4* Wf14 = (const float4*)Wf1;
  for (int i = t; i < 2048; i += 256){          // Wf1 (64x128)
    float4 v = Wf14[i];
    int d = i >> 5, j = (i & 31) * 4;
    Wf1t[(j+0)*72+d]=f2bf(v.x); Wf1t[(j+1)*72+d]=f2bf(v.y);
    Wf1t[(j+2)*72+d]=f2bf(v.z); Wf1t[(j+3)*72+d]=f2bf(v.w);
  }
  const float4* Wf24 = (const float4*)Wf2;
  for (int i = t; i < 2048; i += 256){          // Wf2 (128x64)
    float4 v = Wf24[i];
    int kx = i >> 4, n = (i & 15) * 4;
    Wf2t[(n+0)*136+kx]=f2bf(v.x); Wf2t[(n+1)*136+kx]=f2bf(v.y);
    Wf2t[(n+2)*136+kx]=f2bf(v.z); Wf2t[(n+3)*136+kx]=f2bf(v.w);
  }
  const float4* Ws14 = (const float4*)Ws1;
  for (int i = t; i < 512; i += 256){           // Ws1 (64x32)
    float4 v = Ws14[i];
    int d = i >> 3, c0 = (i & 7) * 4;
    Ws1t[(c0+0)*72+d]=f2bf(v.x); Ws1t[(c0+1)*72+d]=f2bf(v.y);
    Ws1t[(c0+2)*72+d]=f2bf(v.z); Ws1t[(c0+3)*72+d]=f2bf(v.w);
  }
  if (t < 128) cb[t] = bf1[t];
  if (t < 64){ cb[128+t] = bf2[t]; cb[192+t] = lng[t]; cb[256+t] = lnb[t]; }
  if (t < 32){ cb[320+t] = bs1[t]; cb[352+t] = Ws2[t]; }

  // ---- QK^T (needs no LDS -> runs while staging drains) ----
  int qrow0 = qt*16;
  const unsigned short* qp = q    + b*32768;
  const unsigned short* kp = kmat + b*32768;
  const unsigned short* vp = vt   + b*32768;

  s16x8 aq0 = ld8(qp + (qrow0+colL)*64 +  0 + quad*8);
  s16x8 aq1 = ld8(qp + (qrow0+colL)*64 + 32 + quad*8);

  int key0 = wave*128;
  f32x4 S[8];
#pragma unroll
  for (int mt = 0; mt < 8; ++mt){
    int key = key0 + mt*16 + colL;
    f32x4 c = {};
    c = mfma16(aq0, ld8(kp + key*64 +  0 + quad*8), c);
    c = mfma16(aq1, ld8(kp + key*64 + 32 + quad*8), c);
    S[mt] = c;
  }
  __syncthreads();   // r_s/rt_s ready (staging drained under QK^T)

  int rq[4];
#pragma unroll
  for (int i = 0; i < 4; ++i) rq[i] = r_s[qrow0 + quad*4 + i];

  float rmax[4] = {-1e30f,-1e30f,-1e30f,-1e30f};
#pragma unroll
  for (int mt = 0; mt < 8; ++mt){
    int rm = r_s[key0 + mt*16 + colL];
#pragma unroll
    for (int i = 0; i < 4; ++i){
      int dd = rq[i] - rm; dd = dd < 0 ? -dd : dd; dd = dd > 50 ? 50 : dd;
      float s = S[mt][i] * 0.125f * rt_s[dd];
      S[mt][i] = s;
      rmax[i] = fmaxf(rmax[i], s);
    }
  }
#pragma unroll
  for (int i = 0; i < 4; ++i){
    rmax[i] = fmaxf(rmax[i], __shfl_xor(rmax[i], 1));
    rmax[i] = fmaxf(rmax[i], __shfl_xor(rmax[i], 2));
    rmax[i] = fmaxf(rmax[i], __shfl_xor(rmax[i], 4));
    rmax[i] = fmaxf(rmax[i], __shfl_xor(rmax[i], 8));
  }
  if (colL == 0){
#pragma unroll
    for (int i = 0; i < 4; ++i) pmax_s[wave][quad*4 + i] = rmax[i];
  }
  __syncthreads();
  float gmax[4];
#pragma unroll
  for (int i = 0; i < 4; ++i){
    int r = quad*4 + i;
    gmax[i] = fmaxf(fmaxf(pmax_s[0][r], pmax_s[1][r]), fmaxf(pmax_s[2][r], pmax_s[3][r]));
  }
  float rsum[4] = {0.f,0.f,0.f,0.f};
#pragma unroll
  for (int mt = 0; mt < 8; ++mt){
#pragma unroll
    for (int i = 0; i < 4; ++i){
      float p = __expf(S[mt][i] - gmax[i]);
      S[mt][i] = p;
      rsum[i] += p;
    }
  }
#pragma unroll
  for (int i = 0; i < 4; ++i){
    rsum[i] += __shfl_xor(rsum[i], 1);
    rsum[i] += __shfl_xor(rsum[i], 2);
    rsum[i] += __shfl_xor(rsum[i], 4);
    rsum[i] += __shfl_xor(rsum[i], 8);
  }
  if (colL == 0){
#pragma unroll
    for (int i = 0; i < 4; ++i) psum_s[wave][quad*4 + i] = rsum[i];
  }
  __syncthreads();
  float inv[4];
#pragma unroll
  for (int i = 0; i < 4; ++i){
    int r = quad*4 + i;
    inv[i] = 1.f / (psum_s[0][r] + psum_s[1][r] + psum_s[2][r] + psum_s[3][r]);
  }
  unsigned short* Pw = Pbuf + wave*(16*136);
#pragma unroll
  for (int mt = 0; mt < 8; ++mt){
#pragma unroll
    for (int i = 0; i < 4; ++i)
      Pw[(quad*4+i)*136 + mt*16 + colL] = f2bf(S[mt][i] * inv[i]);
  }
  // PV on own-wave P (no barrier needed)
  f32x4 O[4] = {};
#pragma unroll
  for (int mc = 0; mc < 128; mc += 32){
    s16x8 ap = ld8(&Pw[colL*136 + mc + quad*8]);
#pragma unroll
    for (int dt = 0; dt < 4; ++dt)
      O[dt] = mfma16(ap, ld8(vp + (dt*16+colL)*512 + key0 + mc + quad*8), O[dt]);
  }
  float* Ow = Opart[wave];
#pragma unroll
  for (int dt = 0; dt < 4; ++dt)
#pragma unroll
    for (int i = 0; i < 4; ++i)
      Ow[(quad*4+i)*66 + dt*16 + colL] = O[dt][i];
  __syncthreads();             // P dead from here; reuse Pbuf as aoS/hbuf
  unsigned short* aoS = Pbuf;  // 16x72
  for (int e = t; e < 1024; e += 256){
    int row = e >> 6, col = e & 63;
    float s = Opart[0][row*66+col] + Opart[1][row*66+col]
            + Opart[2][row*66+col] + Opart[3][row*66+col];
    aoS[row*72 + col] = f2bf(s);
  }
  __syncthreads();

  // ---- FFN + LayerNorm + head on this block's 16 rows (wave 0) ----
  if (wave == 0){
    unsigned short* hw = Pbuf + 2176;   // 16x136 scratch (old P[1] region)
    int row0g = b*512 + qt*16;

    f32x4 a1[8] = {};
#pragma unroll
    for (int kc = 0; kc < 64; kc += 32){
      s16x8 a = ld8(&aoS[colL*72 + kc + quad*8]);
#pragma unroll
      for (int nt = 0; nt < 8; ++nt)
        a1[nt] = mfma16(a, ld8(&Wf1t[(nt*16+colL)*72 + kc + quad*8]), a1[nt]);
    }
#pragma unroll
    for (int nt = 0; nt < 8; ++nt){
      int col = nt*16 + colL;
      float bb = cb[col];
#pragma unroll
      for (int i = 0; i < 4; ++i)
        hw[(quad*4+i)*136 + col] = f2bf(fmaxf(a1[nt][i] + bb, 0.f));
    }
    f32x4 a2[4] = {};
#pragma unroll
    for (int kc = 0; kc < 128; kc += 32){
      s16x8 a = ld8(&hw[colL*136 + kc + quad*8]);
#pragma unroll
      for (int nt = 0; nt < 4; ++nt)
        a2[nt] = mfma16(a, ld8(&Wf2t[(nt*16+colL)*136 + kc + quad*8]), a2[nt]);
    }
    float vals[4][4];
#pragma unroll
    for (int nt = 0; nt < 4; ++nt){
      float bb = cb[128 + nt*16 + colL];
#pragma unroll
      for (int i = 0; i < 4; ++i) vals[i][nt] = a2[nt][i] + bb;
    }
    float hnv[4][4];
#pragma unroll
    for (int i = 0; i < 4; ++i){
      float s = vals[i][0]+vals[i][1]+vals[i][2]+vals[i][3];
      s += __shfl_xor(s,1); s += __shfl_xor(s,2); s += __shfl_xor(s,4); s += __shfl_xor(s,8);
      float mu = s * (1.f/64.f);
      float d0=vals[i][0]-mu, d1=vals[i][1]-mu, d2=vals[i][2]-mu, d3=vals[i][3]-mu;
      float s2 = d0*d0 + d1*d1 + d2*d2 + d3*d3;
      s2 += __shfl_xor(s2,1); s2 += __shfl_xor(s2,2); s2 += __shfl_xor(s2,4); s2 += __shfl_xor(s2,8);
      float invs = rsqrtf(s2*(1.f/64.f) + 1e-5f);
#pragma unroll
      for (int nt = 0; nt < 4; ++nt){
        int col = nt*16 + colL;
        hnv[i][nt] = (vals[i][nt]-mu)*invs*cb[192+col] + cb[256+col];
      }
    }
#pragma unroll
    for (int i = 0; i < 4; ++i)
#pragma unroll
      for (int nt = 0; nt < 4; ++nt)
        hw[(quad*4+i)*72 + nt*16 + colL] = f2bf(hnv[i][nt]);

    f32x4 a3[2] = {};
#pragma unroll
    for (int kc = 0; kc < 64; kc += 32){
      s16x8 a = ld8(&hw[colL*72 + kc + quad*8]);
#pragma unroll
      for (int nt = 0; nt < 2; ++nt)
        a3[nt] = mfma16(a, ld8(&Ws1t[(nt*16+colL)*72 + kc + quad*8]), a3[nt]);
    }
    float bs2f = bs2[0];
#pragma unroll
    for (int i = 0; i < 4; ++i){
      float p = 0.f;
#pragma unroll
      for (int nt = 0; nt < 2; ++nt){
        int col = nt*16 + colL;
        p += fmaxf(a3[nt][i] + cb[320+col], 0.f) * cb[352+col];
      }
      p += __shfl_xor(p,1); p += __shfl_xor(p,2); p += __shfl_xor(p,4); p += __shfl_xor(p,8);
      if (colL == 0){
        float z = p + bs2f;
        out[row0g + quad*4 + i] = 1.f / (1.f + __expf(-z));
      }
    }
  }
}

extern "C" void kernel_launch(void* const* d_in, const int* in_sizes, int n_in,
                              void* d_out, int out_size, void* d_ws, size_t ws_size,
                              hipStream_t stream)
{
  const float* x    = (const float*)d_in[0];
  const int*   rank = (const int*)d_in[1];
  const float* Wp   = (const float*)d_in[2];
  const float* bp   = (const float*)d_in[3];
  const float* Wq   = (const float*)d_in[4];
  const float* bq   = (const float*)d_in[5];
  const float* Wk   = (const float*)d_in[6];
  const float* bk   = (const float*)d_in[7];
  const float* Wv   = (const float*)d_in[8];
  const float* bv   = (const float*)d_in[9];
  const float* Ee   = (const float*)d_in[10];
  const float* Wr1  = (const float*)d_in[11];
  const float* br1  = (const float*)d_in[12];
  const float* Wr2  = (const float*)d_in[13];
  const float* Wf1  = (const float*)d_in[14];
  const float* bf1  = (const float*)d_in[15];
  const float* Wf2  = (const float*)d_in[16];
  const float* bf2  = (const float*)d_in[17];
  const float* lng  = (const float*)d_in[18];
  const float* lnb  = (const float*)d_in[19];
  const float* Ws1  = (const float*)d_in[20];
  const float* bs1  = (const float*)d_in[21];
  const float* Ws2  = (const float*)d_in[22];
  const float* bs2  = (const float*)d_in[23];
  float* out = (float*)d_out;

  char* ws = (char*)d_ws;
  float*          rel_t = (float*)(ws + 0);
  unsigned short* q     = (unsigned short*)(ws + 256);
  unsigned short* kk    = (unsigned short*)(ws + 256 + 1*1048576);
  unsigned short* vt    = (unsigned short*)(ws + 256 + 2*1048576);

  k_proj<<<dim3(256), dim3(192), 0, stream>>>(x, Wp, bp, Wq, bq, Wk, bk, Wv, bv,
                                              Ee, Wr1, br1, Wr2, q, kk, vt, rel_t);
  k_attn_ffn<<<dim3(32, 16), dim3(256), 0, stream>>>(q, kk, vt, rank, rel_t,
                                              Wf1, bf1, Wf2, bf2, lng, lnb,
                                              Ws1, bs1, Ws2, bs2, out);
}

// Round 3
// 131.928 us; speedup vs baseline: 2.1052x; 1.0314x over previous
//
#include <hip/hip_runtime.h>

using f32x4 = __attribute__((ext_vector_type(4))) float;
using s16x8 = __attribute__((ext_vector_type(8))) short;

static __device__ __forceinline__ unsigned short f2bf(float f){
  union { float f; unsigned int i; } c; c.f = f;
  return (unsigned short)((c.i + 0x7FFFu + ((c.i >> 16) & 1u)) >> 16);
}
static __device__ __forceinline__ s16x8 ld8(const unsigned short* p){
  return *(const s16x8*)p;
}
static __device__ __forceinline__ s16x8 cvt8(const float* p){
  const float4* q = (const float4*)p;
  float4 a = q[0], b = q[1];
  s16x8 r;
  r[0]=(short)f2bf(a.x); r[1]=(short)f2bf(a.y); r[2]=(short)f2bf(a.z); r[3]=(short)f2bf(a.w);
  r[4]=(short)f2bf(b.x); r[5]=(short)f2bf(b.y); r[6]=(short)f2bf(b.z); r[7]=(short)f2bf(b.w);
  return r;
}
static __device__ __forceinline__ f32x4 mfma16(s16x8 a, s16x8 b, f32x4 c){
  return __builtin_amdgcn_mfma_f32_16x16x32_bf16(a, b, c, 0, 0, 0);
}

// ============ k_prep: one-shot weight transpose f32->bf16 + cb pack + rel table ============
// grid 64 x 256. Source loads coalesced; dest scatter is tiny (~94 KB total).
__global__ __launch_bounds__(256) void k_prep(
    const float* __restrict__ Wp, const float* __restrict__ Wq,
    const float* __restrict__ Wk, const float* __restrict__ Wv,
    const float* __restrict__ Ee, const float* __restrict__ Wr1,
    const float* __restrict__ br1, const float* __restrict__ Wr2,
    const float* __restrict__ Wf1, const float* __restrict__ bf1,
    const float* __restrict__ Wf2, const float* __restrict__ bf2,
    const float* __restrict__ lng, const float* __restrict__ lnb,
    const float* __restrict__ Ws1, const float* __restrict__ bs1,
    const float* __restrict__ Ws2, const float* __restrict__ bs2,
    unsigned short* __restrict__ wpt, unsigned short* __restrict__ wqt,
    unsigned short* __restrict__ wkt, unsigned short* __restrict__ wvt,
    unsigned short* __restrict__ wf1t, unsigned short* __restrict__ wf2t,
    unsigned short* __restrict__ ws1t, float* __restrict__ cbp,
    float* __restrict__ rel_t)
{
  int g = blockIdx.x*256 + threadIdx.x;          // [0, 16384)
  // Wp (256x64) -> WpT [n][k] stride 256
  { int e = g; wpt[(e&63)*256 + (e>>6)] = f2bf(Wp[e]); }
  // Wq/Wk/Wv (64x64) -> [n][k] stride 64
  if (g < 4096){
    int e = g, n = e & 63, k = e >> 6;
    wqt[n*64 + k] = f2bf(Wq[e]);
    wkt[n*64 + k] = f2bf(Wk[e]);
    wvt[n*64 + k] = f2bf(Wv[e]);
  }
  // Wf1 (64x128) -> [j][d] stride 64 ; Wf2 (128x64) -> [n][k] stride 128
  if (g < 8192){
    int e = g;
    wf1t[(e&127)*64 + (e>>7)] = f2bf(Wf1[e]);
    wf2t[(e&63)*128 + (e>>6)] = f2bf(Wf2[e]);
  }
  // Ws1 (64x32) -> [c][d] stride 64
  if (g < 2048) ws1t[(g&31)*64 + (g>>5)] = f2bf(Ws1[g]);
  // cb pack: 385 f32
  if (g >= 8192 && g < 8577){
    int u = g - 8192; float v;
    if      (u < 128) v = bf1[u];
    else if (u < 192) v = bf2[u-128];
    else if (u < 256) v = lng[u-192];
    else if (u < 320) v = lnb[u-256];
    else if (u < 352) v = bs1[u-320];
    else if (u < 384) v = Ws2[u-352];
    else              v = bs2[0];
    cbp[u] = v;
  }
  // rel table (51 entries)
  if (g >= 8704 && g < 8755){
    int dd = g - 8704;
    float e[32];
    const float4* e4 = (const float4*)(Ee + dd*32);
#pragma unroll
    for (int j = 0; j < 8; ++j){
      float4 v = e4[j];
      e[j*4+0]=v.x; e[j*4+1]=v.y; e[j*4+2]=v.z; e[j*4+3]=v.w;
    }
    float w = 0.f;
    for (int h = 0; h < 16; ++h){
      float s = br1[h];
#pragma unroll
      for (int j = 0; j < 32; ++j) s += e[j] * Wr1[j*16 + h];
      w += fmaxf(s, 0.f) * Wr2[h];
    }
    rel_t[dd] = 1.f / (1.f + __expf(-w));
  }
}

// ============ k_proj: staging-free; B-fragments ld8 direct from bf16 global ============
// grid 256 x 128 (2 waves x 16 rows). LDS only for the per-wave xp handoff.
__global__ __launch_bounds__(128) void k_proj(const float* __restrict__ x,
    const float* __restrict__ bp, const float* __restrict__ bq,
    const float* __restrict__ bk, const float* __restrict__ bv,
    const unsigned short* __restrict__ wpt, const unsigned short* __restrict__ wqt,
    const unsigned short* __restrict__ wkt, const unsigned short* __restrict__ wvt,
    unsigned short* __restrict__ q, unsigned short* __restrict__ kk,
    unsigned short* __restrict__ vt)
{
  __shared__ __align__(16) unsigned short xs[2][16*72];

  int t = threadIdx.x, lane = t & 63, wave = t >> 6;
  int colL = lane & 15, quad = lane >> 4;
  int row0 = blockIdx.x*32 + wave*16;

  // xp = x @ Wp + bp ; A from x (cold HBM), B frags from L3-hot bf16 WpT
  const float* xr = x + (row0 + colL)*256;
  f32x4 acc[4] = {};
#pragma unroll
  for (int kc = 0; kc < 256; kc += 32){
    s16x8 a = cvt8(xr + kc + quad*8);
#pragma unroll
    for (int nt = 0; nt < 4; ++nt)
      acc[nt] = mfma16(a, ld8(&wpt[(nt*16+colL)*256 + kc + quad*8]), acc[nt]);
  }
  unsigned short* xw = xs[wave];
#pragma unroll
  for (int nt = 0; nt < 4; ++nt){
    int col = nt*16 + colL;
    float bb = bp[col];
#pragma unroll
    for (int i = 0; i < 4; ++i)
      xw[(quad*4+i)*72 + col] = f2bf(acc[nt][i] + bb);
  }
  // own-wave LDS write->read: compiler inserts lgkmcnt wait; no barrier needed
  s16x8 a0 = ld8(&xw[colL*72 +  0 + quad*8]);
  s16x8 a1 = ld8(&xw[colL*72 + 32 + quad*8]);

#pragma unroll
  for (int w = 0; w < 3; ++w){
    const float* bias = w==0 ? bq : (w==1 ? bk : bv);
    const unsigned short* Wt = w==0 ? wqt : (w==1 ? wkt : wvt);
    f32x4 c[4] = {};
#pragma unroll
    for (int nt = 0; nt < 4; ++nt){
      c[nt] = mfma16(a0, ld8(&Wt[(nt*16+colL)*64 +  0 + quad*8]), c[nt]);
      c[nt] = mfma16(a1, ld8(&Wt[(nt*16+colL)*64 + 32 + quad*8]), c[nt]);
    }
#pragma unroll
    for (int nt = 0; nt < 4; ++nt){
      int col = nt*16 + colL;
      float bb = bias[col];
#pragma unroll
      for (int i = 0; i < 4; ++i){
        int row = row0 + quad*4 + i;
        float v = c[nt][i] + bb;
        if (w == 0)      q [row*64 + col] = f2bf(v);
        else if (w == 1) kk[row*64 + col] = f2bf(v);
        else             vt[(row>>9)*32768 + col*512 + (row & 511)] = f2bf(v);
      }
    }
  }
}

// ============ k_attn_ffn: staging-free attention + FFN + LN + head ============
// grid (32 qtiles, 16 batches) x 256thr; 4-way key split; ao stays in LDS.
// FFN weight fragments ld8 direct from L3-hot bf16 global. LDS ~39 KB.
__global__ __launch_bounds__(256) void k_attn_ffn(const unsigned short* __restrict__ q,
    const unsigned short* __restrict__ kmat, const unsigned short* __restrict__ vt,
    const int* __restrict__ ranks, const float* __restrict__ rel_t,
    const unsigned short* __restrict__ wf1t, const unsigned short* __restrict__ wf2t,
    const unsigned short* __restrict__ ws1t, const float* __restrict__ cbp,
    float* __restrict__ out)
{
  __shared__ __align__(16) int r_s[512];
  __shared__ float rt_s[64];
  __shared__ float pmax_s[4][16], psum_s[4][16];
  __shared__ __align__(16) unsigned short Pbuf[4*16*136]; // P; later aoS(@0)+hbuf(@2176)
  __shared__ __align__(16) float Opart[4][16*66];
  __shared__ float cb[388];

  int b = blockIdx.y, qt = blockIdx.x;
  int t = threadIdx.x, lane = t & 63, wave = t >> 6;
  int colL = lane & 15, quad = lane >> 4;

  // ---- tiny staging (ranks / rel table / packed cb), overlaps QK^T ----
  if (t < 128) ((int4*)r_s)[t] = ((const int4*)(ranks + b*512))[t];
  if (t < 64) rt_s[t] = (t < 51) ? rel_t[t] : 0.f;
  if (t >= 64 && t < 161){
    int u = t - 64;
    if (u < 96) ((float4*)cb)[u] = ((const float4*)cbp)[u];
    else        cb[384] = cbp[384];
  }

  // ---- QK^T ----
  int qrow0 = qt*16;
  const unsigned short* qp = q    + b*32768;
  const unsigned short* kp = kmat + b*32768;
  const unsigned short* vp = vt   + b*32768;

  s16x8 aq0 = ld8(qp + (qrow0+colL)*64 +  0 + quad*8);
  s16x8 aq1 = ld8(qp + (qrow0+colL)*64 + 32 + quad*8);

  int key0 = wave*128;
  f32x4 S[8];
#pragma unroll
  for (int mt = 0; mt < 8; ++mt){
    int key = key0 + mt*16 + colL;
    f32x4 c = {};
    c = mfma16(aq0, ld8(kp + key*64 +  0 + quad*8), c);
    c = mfma16(aq1, ld8(kp + key*64 + 32 + quad*8), c);
    S[mt] = c;
  }
  __syncthreads();   // r_s/rt_s/cb ready

  int rq[4];
#pragma unroll
  for (int i = 0; i < 4; ++i) rq[i] = r_s[qrow0 + quad*4 + i];

  float rmax[4] = {-1e30f,-1e30f,-1e30f,-1e30f};
#pragma unroll
  for (int mt = 0; mt < 8; ++mt){
    int rm = r_s[key0 + mt*16 + colL];
#pragma unroll
    for (int i = 0; i < 4; ++i){
      int dd = rq[i] - rm; dd = dd < 0 ? -dd : dd; dd = dd > 50 ? 50 : dd;
      float s = S[mt][i] * 0.125f * rt_s[dd];
      S[mt][i] = s;
      rmax[i] = fmaxf(rmax[i], s);
    }
  }
#pragma unroll
  for (int i = 0; i < 4; ++i){
    rmax[i] = fmaxf(rmax[i], __shfl_xor(rmax[i], 1));
    rmax[i] = fmaxf(rmax[i], __shfl_xor(rmax[i], 2));
    rmax[i] = fmaxf(rmax[i], __shfl_xor(rmax[i], 4));
    rmax[i] = fmaxf(rmax[i], __shfl_xor(rmax[i], 8));
  }
  if (colL == 0){
#pragma unroll
    for (int i = 0; i < 4; ++i) pmax_s[wave][quad*4 + i] = rmax[i];
  }
  __syncthreads();
  float gmax[4];
#pragma unroll
  for (int i = 0; i < 4; ++i){
    int r = quad*4 + i;
    gmax[i] = fmaxf(fmaxf(pmax_s[0][r], pmax_s[1][r]), fmaxf(pmax_s[2][r], pmax_s[3][r]));
  }
  float rsum[4] = {0.f,0.f,0.f,0.f};
#pragma unroll
  for (int mt = 0; mt < 8; ++mt){
#pragma unroll
    for (int i = 0; i < 4; ++i){
      float p = __expf(S[mt][i] - gmax[i]);
      S[mt][i] = p;
      rsum[i] += p;
    }
  }
#pragma unroll
  for (int i = 0; i < 4; ++i){
    rsum[i] += __shfl_xor(rsum[i], 1);
    rsum[i] += __shfl_xor(rsum[i], 2);
    rsum[i] += __shfl_xor(rsum[i], 4);
    rsum[i] += __shfl_xor(rsum[i], 8);
  }
  if (colL == 0){
#pragma unroll
    for (int i = 0; i < 4; ++i) psum_s[wave][quad*4 + i] = rsum[i];
  }
  __syncthreads();
  float inv[4];
#pragma unroll
  for (int i = 0; i < 4; ++i){
    int r = quad*4 + i;
    inv[i] = 1.f / (psum_s[0][r] + psum_s[1][r] + psum_s[2][r] + psum_s[3][r]);
  }
  unsigned short* Pw = Pbuf + wave*(16*136);
#pragma unroll
  for (int mt = 0; mt < 8; ++mt){
#pragma unroll
    for (int i = 0; i < 4; ++i)
      Pw[(quad*4+i)*136 + mt*16 + colL] = f2bf(S[mt][i] * inv[i]);
  }
  // PV on own-wave P (no barrier needed)
  f32x4 O[4] = {};
#pragma unroll
  for (int mc = 0; mc < 128; mc += 32){
    s16x8 ap = ld8(&Pw[colL*136 + mc + quad*8]);
#pragma unroll
    for (int dt = 0; dt < 4; ++dt)
      O[dt] = mfma16(ap, ld8(vp + (dt*16+colL)*512 + key0 + mc + quad*8), O[dt]);
  }
  float* Ow = Opart[wave];
#pragma unroll
  for (int dt = 0; dt < 4; ++dt)
#pragma unroll
    for (int i = 0; i < 4; ++i)
      Ow[(quad*4+i)*66 + dt*16 + colL] = O[dt][i];
  __syncthreads();             // P dead from here; reuse Pbuf as aoS/hbuf
  unsigned short* aoS = Pbuf;  // 16x72
  for (int e = t; e < 1024; e += 256){
    int row = e >> 6, col = e & 63;
    float s = Opart[0][row*66+col] + Opart[1][row*66+col]
            + Opart[2][row*66+col] + Opart[3][row*66+col];
    aoS[row*72 + col] = f2bf(s);
  }
  __syncthreads();

  // ---- FFN + LayerNorm + head on this block's 16 rows (wave 0) ----
  if (wave == 0){
    unsigned short* hw = Pbuf + 2176;   // 16x136 scratch (old P[1] region)
    int row0g = b*512 + qt*16;

    f32x4 a1[8] = {};
#pragma unroll
    for (int kc = 0; kc < 64; kc += 32){
      s16x8 a = ld8(&aoS[colL*72 + kc + quad*8]);
#pragma unroll
      for (int nt = 0; nt < 8; ++nt)
        a1[nt] = mfma16(a, ld8(&wf1t[(nt*16+colL)*64 + kc + quad*8]), a1[nt]);
    }
#pragma unroll
    for (int nt = 0; nt < 8; ++nt){
      int col = nt*16 + colL;
      float bb = cb[col];
#pragma unroll
      for (int i = 0; i < 4; ++i)
        hw[(quad*4+i)*136 + col] = f2bf(fmaxf(a1[nt][i] + bb, 0.f));
    }
    f32x4 a2[4] = {};
#pragma unroll
    for (int kc = 0; kc < 128; kc += 32){
      s16x8 a = ld8(&hw[colL*136 + kc + quad*8]);
#pragma unroll
      for (int nt = 0; nt < 4; ++nt)
        a2[nt] = mfma16(a, ld8(&wf2t[(nt*16+colL)*128 + kc + quad*8]), a2[nt]);
    }
    float vals[4][4];
#pragma unroll
    for (int nt = 0; nt < 4; ++nt){
      float bb = cb[128 + nt*16 + colL];
#pragma unroll
      for (int i = 0; i < 4; ++i) vals[i][nt] = a2[nt][i] + bb;
    }
    float hnv[4][4];
#pragma unroll
    for (int i = 0; i < 4; ++i){
      float s = vals[i][0]+vals[i][1]+vals[i][2]+vals[i][3];
      s += __shfl_xor(s,1); s += __shfl_xor(s,2); s += __shfl_xor(s,4); s += __shfl_xor(s,8);
      float mu = s * (1.f/64.f);
      float d0=vals[i][0]-mu, d1=vals[i][1]-mu, d2=vals[i][2]-mu, d3=vals[i][3]-mu;
      float s2 = d0*d0 + d1*d1 + d2*d2 + d3*d3;
      s2 += __shfl_xor(s2,1); s2 += __shfl_xor(s2,2); s2 += __shfl_xor(s2,4); s2 += __shfl_xor(s2,8);
      float invs = rsqrtf(s2*(1.f/64.f) + 1e-5f);
#pragma unroll
      for (int nt = 0; nt < 4; ++nt){
        int col = nt*16 + colL;
        hnv[i][nt] = (vals[i][nt]-mu)*invs*cb[192+col] + cb[256+col];
      }
    }
#pragma unroll
    for (int i = 0; i < 4; ++i)
#pragma unroll
      for (int nt = 0; nt < 4; ++nt)
        hw[(quad*4+i)*72 + nt*16 + colL] = f2bf(hnv[i][nt]);

    f32x4 a3[2] = {};
#pragma unroll
    for (int kc = 0; kc < 64; kc += 32){
      s16x8 a = ld8(&hw[colL*72 + kc + quad*8]);
#pragma unroll
      for (int nt = 0; nt < 2; ++nt)
        a3[nt] = mfma16(a, ld8(&ws1t[(nt*16+colL)*64 + kc + quad*8]), a3[nt]);
    }
    float bs2f = cb[384];
#pragma unroll
    for (int i = 0; i < 4; ++i){
      float p = 0.f;
#pragma unroll
      for (int nt = 0; nt < 2; ++nt){
        int col = nt*16 + colL;
        p += fmaxf(a3[nt][i] + cb[320+col], 0.f) * cb[352+col];
      }
      p += __shfl_xor(p,1); p += __shfl_xor(p,2); p += __shfl_xor(p,4); p += __shfl_xor(p,8);
      if (colL == 0){
        float z = p + bs2f;
        out[row0g + quad*4 + i] = 1.f / (1.f + __expf(-z));
      }
    }
  }
}

extern "C" void kernel_launch(void* const* d_in, const int* in_sizes, int n_in,
                              void* d_out, int out_size, void* d_ws, size_t ws_size,
                              hipStream_t stream)
{
  const float* x    = (const float*)d_in[0];
  const int*   rank = (const int*)d_in[1];
  const float* Wp   = (const float*)d_in[2];
  const float* bp   = (const float*)d_in[3];
  const float* Wq   = (const float*)d_in[4];
  const float* bq   = (const float*)d_in[5];
  const float* Wk   = (const float*)d_in[6];
  const float* bk   = (const float*)d_in[7];
  const float* Wv   = (const float*)d_in[8];
  const float* bv   = (const float*)d_in[9];
  const float* Ee   = (const float*)d_in[10];
  const float* Wr1  = (const float*)d_in[11];
  const float* br1  = (const float*)d_in[12];
  const float* Wr2  = (const float*)d_in[13];
  const float* Wf1  = (const float*)d_in[14];
  const float* bf1  = (const float*)d_in[15];
  const float* Wf2  = (const float*)d_in[16];
  const float* bf2  = (const float*)d_in[17];
  const float* lng  = (const float*)d_in[18];
  const float* lnb  = (const float*)d_in[19];
  const float* Ws1  = (const float*)d_in[20];
  const float* bs1  = (const float*)d_in[21];
  const float* Ws2  = (const float*)d_in[22];
  const float* bs2  = (const float*)d_in[23];
  float* out = (float*)d_out;

  char* ws = (char*)d_ws;
  float*          rel_t = (float*)(ws + 0);
  unsigned short* q     = (unsigned short*)(ws + 256);
  unsigned short* kk    = (unsigned short*)(ws + 256 + 1*1048576);
  unsigned short* vt    = (unsigned short*)(ws + 256 + 2*1048576);
  unsigned short* wpt   = (unsigned short*)(ws + 3145984);
  unsigned short* wqt   = (unsigned short*)(ws + 3178752);
  unsigned short* wkt   = (unsigned short*)(ws + 3186944);
  unsigned short* wvt   = (unsigned short*)(ws + 3195136);
  unsigned short* wf1t  = (unsigned short*)(ws + 3203328);
  unsigned short* wf2t  = (unsigned short*)(ws + 3219712);
  unsigned short* ws1t  = (unsigned short*)(ws + 3236096);
  float*          cbp   = (float*)(ws + 3240192);

  k_prep<<<dim3(64), dim3(256), 0, stream>>>(Wp, Wq, Wk, Wv, Ee, Wr1, br1, Wr2,
                                             Wf1, bf1, Wf2, bf2, lng, lnb,
                                             Ws1, bs1, Ws2, bs2,
                                             wpt, wqt, wkt, wvt, wf1t, wf2t, ws1t,
                                             cbp, rel_t);
  k_proj<<<dim3(256), dim3(128), 0, stream>>>(x, bp, bq, bk, bv,
                                              wpt, wqt, wkt, wvt, q, kk, vt);
  k_attn_ffn<<<dim3(32, 16), dim3(256), 0, stream>>>(q, kk, vt, rank, rel_t,
                                              wf1t, wf2t, ws1t, cbp, out);
}